// Round 7
// baseline (61.239 us; speedup 1.0000x reference)
//
#include <hip/hip_runtime.h>
#include <stdint.h>

#define B_ 4
#define N_ 2048
#define K_ 30
#define F_ 128
#define NF 39

typedef unsigned long long u64;
typedef float f32x4 __attribute__((ext_vector_type(4)));
typedef short s16x8 __attribute__((ext_vector_type(8)));

__device__ __forceinline__ u64 umin64(u64 a, u64 b) { return a < b ? a : b; }
__device__ __forceinline__ u64 umax64(u64 a, u64 b) { return a > b ? a : b; }

template <int CTRL>
__device__ __forceinline__ float dpp_add(float x) {
    int r = __builtin_amdgcn_update_dpp(0, __float_as_int(x), CTRL, 0xF, 0xF, true);
    return x + __int_as_float(r);
}
// sum over the 16 lanes of a DPP row (all lanes get the row total)
__device__ __forceinline__ float rowsum16(float x) {
    x = dpp_add<0xB1>(x);    // quad_perm [1,0,3,2]
    x = dpp_add<0x4E>(x);    // quad_perm [2,3,0,1]
    x = dpp_add<0x141>(x);   // row_half_mirror
    x = dpp_add<0x140>(x);   // row_mirror
    return x;
}

__device__ __forceinline__ unsigned int bf16rne(float f) {
    unsigned int u = __float_as_uint(f);
    return (u + 0x7FFFu + ((u >> 16) & 1u)) >> 16;
}
__device__ __forceinline__ unsigned int bfpack(float a, float b) {
    return bf16rne(a) | (bf16rne(b) << 16);
}

// orientation frame (o1, n2, o1 x n2) of node ii, from LDS coords
__device__ __forceinline__ void frame_from(const float4* Pp, int ii, float o[9]) {
    #pragma unroll
    for (int q = 0; q < 9; ++q) o[q] = 0.f;
    if (ii >= 1 && ii <= N_ - 3) {
        float4 A = Pp[ii-1], Bv = Pp[ii], C = Pp[ii+1];
        float u2x = Bv.x-A.x, u2y = Bv.y-A.y, u2z = Bv.z-A.z;
        float n2_ = sqrtf(u2x*u2x+u2y*u2y+u2z*u2z);
        float inv = 1.0f / fmaxf(n2_, 1e-12f);
        u2x*=inv; u2y*=inv; u2z*=inv;
        float u1x = C.x-Bv.x, u1y = C.y-Bv.y, u1z = C.z-Bv.z;
        float n1_ = sqrtf(u1x*u1x+u1y*u1y+u1z*u1z);
        inv = 1.0f / fmaxf(n1_, 1e-12f);
        u1x*=inv; u1y*=inv; u1z*=inv;
        float nx = u2y*u1z - u2z*u1y;
        float ny = u2z*u1x - u2x*u1z;
        float nz = u2x*u1y - u2y*u1x;
        float nn2 = sqrtf(nx*nx+ny*ny+nz*nz);
        inv = 1.0f / fmaxf(nn2, 1e-12f);
        nx*=inv; ny*=inv; nz*=inv;
        float ox = u2x-u1x, oy = u2y-u1y, oz = u2z-u1z;
        float no = sqrtf(ox*ox+oy*oy+oz*oz);
        inv = 1.0f / fmaxf(no, 1e-12f);
        ox*=inv; oy*=inv; oz*=inv;
        o[0]=ox; o[1]=oy; o[2]=oz;
        o[3]=nx; o[4]=ny; o[5]=nz;
        o[6]=oy*nz - oz*ny; o[7]=oz*nx - ox*nz; o[8]=ox*ny - oy*nx;
    }
}

// ---- Fully fused: topk (wave/node) -> features -> bf16 MFMA GEMM -> LN ----
// block = 4 consecutive nodes = 120 edges (E rows blockIdx*120 .. +119).
__global__ __launch_bounds__(256) void fused_kernel(const float* __restrict__ X,
                                                    const float* __restrict__ W,
                                                    const float* __restrict__ bias,
                                                    const float* __restrict__ gamma,
                                                    const float* __restrict__ beta,
                                                    float* __restrict__ E,
                                                    float* __restrict__ EidxF) {
    // 32 KB region: phase A = float4 P[2048]; phase B = ldsF(16KB) + ldsW(16KB)
    __shared__ __align__(16) unsigned char shraw[32768];
    float4* P = (float4*)shraw;
    unsigned int* ldsF = (unsigned int*)shraw;              // [128 rows][32 uints]
    unsigned int* ldsW = (unsigned int*)(shraw + 16384);    // [128 cols][32 uints]
    __shared__ u64 surv[4][64];
    __shared__ int   idxL[4][32];
    __shared__ float DL[4][32];

    int t = threadIdx.x, lane = t & 63, wid = t >> 6;
    int node = blockIdx.x * 4 + wid;
    int i = node & (N_ - 1);
    const float* Xb = X + (size_t)(node - i) * 3;   // batch base
    float* Pf = (float*)P;

    // ---- phase A0: stage X[batch] into LDS (float4 per node) ----
    for (int idx = t; idx < 3 * N_; idx += 256) {
        float v = Xb[idx];
        int j = idx / 3, c = idx - 3 * j;
        Pf[4 * j + c] = v;
    }
    __syncthreads();

    // ---- phase A1: top-30 per wave (bits(ssq+eps) cutoff, verified r5/r6) ----
    float4 ci = P[i];
    float xi = ci.x, yi = ci.y, zi = ci.z;

    unsigned int d[32];
    #pragma unroll
    for (int s = 0; s < 32; ++s) {
        float4 p = P[lane + (s << 6)];
        float dx = __fsub_rn(p.x, xi);
        float dy = __fsub_rn(p.y, yi);
        float dz = __fsub_rn(p.z, zi);
        float s1 = __fadd_rn(__fmul_rn(dx,dx), __fmul_rn(dy,dy));
        float s2 = __fadd_rn(s1, __fmul_rn(dz,dz));
        d[s] = __float_as_uint(__fadd_rn(s2, 1e-6f));   // bits(ssq+eps)
    }

    unsigned int lm = d[0];
    #pragma unroll
    for (int s = 1; s < 32; ++s) lm = min(lm, d[s]);

    unsigned int v32 = lm;
    #pragma unroll
    for (int k = 2; k <= 64; k <<= 1) {
        #pragma unroll
        for (int j = k >> 1; j >= 1; j >>= 1) {
            unsigned int o = (unsigned int)__shfl_xor((int)v32, j, 64);
            bool up = ((lane & k) == 0);
            bool lower = ((lane & j) == 0);
            v32 = (lower == up) ? min(v32, o) : max(v32, o);
        }
    }
    unsigned int Bcut = (unsigned int)__shfl((int)v32, K_ - 1, 64) + 64u;  // slack

    surv[wid][lane] = ~0ull;
    int base = 0;
    #pragma unroll
    for (int s = 0; s < 32; ++s) {
        bool p = (d[s] <= Bcut);
        u64 blt = __ballot(p);
        if (p) {
            int slot = base + (int)__popcll(blt & ((1ull << lane) - 1ull));
            if (slot < 64) {
                float D = __fsqrt_rn(__uint_as_float(d[s]));   // exact reference D
                surv[wid][slot] = (((u64)__float_as_uint(D)) << 32)
                                | (unsigned int)(lane + (s << 6));
            }
        }
        base += (int)__popcll(blt);
    }
    int cnt = base;

    if (cnt <= 64) {
        u64 v = surv[wid][lane];
        #pragma unroll
        for (int k = 2; k <= 64; k <<= 1) {
            #pragma unroll
            for (int j = k >> 1; j >= 1; j >>= 1) {
                u64 o = (u64)__shfl_xor((long long)v, j, 64);
                bool up = ((lane & k) == 0);
                bool lower = ((lane & j) == 0);
                v = (lower == up) ? umin64(v, o) : umax64(v, o);
            }
        }
        if (lane < K_) {
            int j = (int)(v & 0xffffffffull);
            idxL[wid][lane] = j;
            DL[wid][lane] = __uint_as_float((unsigned int)(v >> 32));
            EidxF[node * K_ + lane] = (float)j;
        }
    } else {
        // exact fallback: convert to D-bits, 30 sequential extractions
        #pragma unroll
        for (int s = 0; s < 32; ++s)
            d[s] = __float_as_uint(__fsqrt_rn(__uint_as_float(d[s])));
        for (int k = 0; k < K_; ++k) {
            u64 m = ~0ull;
            #pragma unroll
            for (int s = 0; s < 32; ++s) {
                u64 kk = (((u64)d[s]) << 32) | (unsigned int)(lane + (s << 6));
                m = umin64(m, kk);
            }
            #pragma unroll
            for (int off = 1; off < 64; off <<= 1)
                m = umin64(m, (u64)__shfl_xor((long long)m, off, 64));
            #pragma unroll
            for (int s = 0; s < 32; ++s) {
                u64 kk = (((u64)d[s]) << 32) | (unsigned int)(lane + (s << 6));
                if (kk == m) d[s] = 0xFFFFFFFFu;
            }
            if (lane == 0) {
                int j = (int)(m & 0xffffffffull);
                idxL[wid][k] = j;
                DL[wid][k] = __uint_as_float((unsigned int)(m >> 32));
                EidxF[node * K_ + k] = (float)j;
            }
        }
    }
    __syncthreads();

    // ---- phase B0: features (threads 0..119, one edge each) in regs;
    //      W load+pack (threads 128..255) in regs. P still live. ----
    uint4 fpack[5];
    uint4 wreg[8];
    float gg[8], be8[8], bb[8];
    #pragma unroll
    for (int tt = 0; tt < 8; ++tt) {
        int c = 16 * tt + (lane & 15);
        gg[tt] = gamma[c]; be8[tt] = beta[c]; bb[tt] = bias[c];
    }

    if (t < 120) {
        int nl = t / 30, k = t - nl * 30;
        int il = (blockIdx.x * 4 + nl) & (N_ - 1);
        int j = idxL[nl][k];
        float dnb = DL[nl][k];

        float f[40];
        float dd = (float)(j - il);
        const float freqs[8] = {1.0f, 0.31622776601683794f, 0.1f, 0.031622776601683794f,
                                0.01f, 0.0031622776601683794f, 0.001f, 0.00031622776601683794f};
        #pragma unroll
        for (int l = 0; l < 8; ++l) {
            float a = dd * freqs[l];
            float sv, cv;
            __sincosf(a, &sv, &cv);
            f[l] = cv;
            f[8 + l] = sv;
        }
        #pragma unroll
        for (int r = 0; r < 16; ++r) {
            float mu = (20.0f / 15.0f) * (float)r;
            float u = (dnb - mu) * 0.8f;
            f[16 + r] = __expf(-u * u);
        }
        float Om[9], On[9];
        frame_from(P, il, Om);
        frame_from(P, j, On);
        float4 Pi = P[il], Pj = P[j];
        float dx = Pj.x - Pi.x, dy = Pj.y - Pi.y, dz = Pj.z - Pi.z;
        float v0 = Om[0]*dx + Om[1]*dy + Om[2]*dz;
        float v1 = Om[3]*dx + Om[4]*dy + Om[5]*dz;
        float v2 = Om[6]*dx + Om[7]*dy + Om[8]*dz;
        float n = sqrtf(v0*v0 + v1*v1 + v2*v2);
        float inv = 1.0f / fmaxf(n, 1e-12f);
        f[32] = v0 * inv; f[33] = v1 * inv; f[34] = v2 * inv;
        float R00 = Om[0]*On[0] + Om[3]*On[3] + Om[6]*On[6];
        float R01 = Om[0]*On[1] + Om[3]*On[4] + Om[6]*On[7];
        float R02 = Om[0]*On[2] + Om[3]*On[5] + Om[6]*On[8];
        float R10 = Om[1]*On[0] + Om[4]*On[3] + Om[7]*On[6];
        float R11 = Om[1]*On[1] + Om[4]*On[4] + Om[7]*On[7];
        float R12 = Om[1]*On[2] + Om[4]*On[5] + Om[7]*On[8];
        float R20 = Om[2]*On[0] + Om[5]*On[3] + Om[8]*On[6];
        float R21 = Om[2]*On[1] + Om[5]*On[4] + Om[8]*On[7];
        float R22 = Om[2]*On[2] + Om[5]*On[5] + Om[8]*On[8];
        float mg0 = 0.5f * sqrtf(fabsf(1.0f + R00 - R11 - R22));
        float mg1 = 0.5f * sqrtf(fabsf(1.0f - R00 + R11 - R22));
        float mg2 = 0.5f * sqrtf(fabsf(1.0f - R00 - R11 + R22));
        float t0 = R21 - R12, t1 = R02 - R20, t2 = R10 - R01;
        float s0 = (t0 > 0.f) ? 1.f : ((t0 < 0.f) ? -1.f : 0.f);
        float s1 = (t1 > 0.f) ? 1.f : ((t1 < 0.f) ? -1.f : 0.f);
        float s2 = (t2 > 0.f) ? 1.f : ((t2 < 0.f) ? -1.f : 0.f);
        float q0 = s0 * mg0, q1 = s1 * mg1, q2 = s2 * mg2;
        float w = sqrtf(fmaxf(1.0f + R00 + R11 + R22, 0.0f)) * 0.5f;
        float nq = sqrtf(q0*q0 + q1*q1 + q2*q2 + w*w);
        inv = 1.0f / fmaxf(nq, 1e-12f);
        f[35] = q0 * inv; f[36] = q1 * inv; f[37] = q2 * inv; f[38] = w * inv;
        f[39] = 0.0f;

        #pragma unroll
        for (int c = 0; c < 5; ++c) {
            fpack[c].x = bfpack(f[8*c+0], f[8*c+1]);
            fpack[c].y = bfpack(f[8*c+2], f[8*c+3]);
            fpack[c].z = bfpack(f[8*c+4], f[8*c+5]);
            fpack[c].w = bfpack(f[8*c+6], f[8*c+7]);
        }
    } else if (t >= 128) {
        int col = t - 128;
        #pragma unroll
        for (int c8 = 0; c8 < 8; ++c8) {
            unsigned int* up = (unsigned int*)&wreg[c8];
            #pragma unroll
            for (int m = 0; m < 4; ++m) {
                int k0 = 8 * c8 + 2 * m, k1 = k0 + 1;
                float a  = (k0 < NF) ? W[k0 * F_ + col] : 0.f;
                float bv = (k1 < NF) ? W[k1 * F_ + col] : 0.f;
                up[m] = bfpack(a, bv);
            }
        }
    }
    __syncthreads();   // all P reads done

    // ---- phase B1: overwrite P region with swizzled bf16 F and W tiles ----
    if (t < 120) {
        int nl = t / 30, k = t - nl * 30;
        int row = nl * 32 + k;               // 2 pad rows per node tile (masked at store)
        #pragma unroll
        for (int c = 0; c < 8; ++c) {
            uint4 u = (c < 5) ? fpack[c] : make_uint4(0u, 0u, 0u, 0u);
            int idx = row * 32 + ((4 * c) ^ ((row & 7) << 2));
            *(uint4*)&ldsF[idx] = u;
        }
    } else if (t >= 128) {
        int col = t - 128;
        #pragma unroll
        for (int c8 = 0; c8 < 8; ++c8) {
            int idx = col * 32 + ((4 * c8) ^ ((col & 7) << 2));
            *(uint4*)&ldsW[idx] = wreg[c8];
        }
    }
    __syncthreads();

    // ---- phase C: MFMA GEMM (64k x 128) + LayerNorm + masked stores ----
    s16x8 wf[8][2];
    #pragma unroll
    for (int tt = 0; tt < 8; ++tt) {
        int col = 16 * tt + (lane & 15);
        #pragma unroll
        for (int s = 0; s < 2; ++s) {
            int idx = col * 32 + ((((lane >> 4) * 4) + s * 16) ^ ((col & 7) << 2));
            wf[tt][s] = *(s16x8*)&ldsW[idx];
        }
    }

    size_t rowbase_g = (size_t)blockIdx.x * 120 + wid * 30;
    #pragma unroll
    for (int wt = 0; wt < 2; ++wt) {
        int arow = wid * 32 + wt * 16 + (lane & 15);
        s16x8 af[2];
        #pragma unroll
        for (int s = 0; s < 2; ++s) {
            int idx = arow * 32 + ((((lane >> 4) * 4) + s * 16) ^ ((arow & 7) << 2));
            af[s] = *(s16x8*)&ldsF[idx];
        }
        f32x4 acc[8];
        #pragma unroll
        for (int tt = 0; tt < 8; ++tt) {
            acc[tt] = (f32x4){0.f, 0.f, 0.f, 0.f};
            acc[tt] = __builtin_amdgcn_mfma_f32_16x16x32_bf16(af[0], wf[tt][0], acc[tt], 0, 0, 0);
            acc[tt] = __builtin_amdgcn_mfma_f32_16x16x32_bf16(af[1], wf[tt][1], acc[tt], 0, 0, 0);
        }
        float sum[4] = {0,0,0,0}, sq[4] = {0,0,0,0};
        #pragma unroll
        for (int tt = 0; tt < 8; ++tt) {
            #pragma unroll
            for (int q = 0; q < 4; ++q) {
                float v = acc[tt][q] + bb[tt];
                acc[tt][q] = v;
                sum[q] += v;
                sq[q] = fmaf(v, v, sq[q]);
            }
        }
        float muv[4], invv[4];
        #pragma unroll
        for (int q = 0; q < 4; ++q) {
            float S  = rowsum16(sum[q]);
            float Qs = rowsum16(sq[q]);
            float mu = S * (1.0f / 128.0f);
            float var = (Qs - S * mu) * (1.0f / 127.0f);
            muv[q] = mu;
            invv[q] = 1.0f / (sqrtf(var + 1e-6f) + 1e-6f);
        }
        #pragma unroll
        for (int tt = 0; tt < 8; ++tt) {
            int c = 16 * tt + (lane & 15);
            #pragma unroll
            for (int q = 0; q < 4; ++q) {
                int local_k = wt * 16 + (lane >> 4) * 4 + q;
                if (local_k < K_) {
                    E[(rowbase_g + local_k) * F_ + c] =
                        gg[tt] * (acc[tt][q] - muv[q]) * invv[q] + be8[tt];
                }
            }
        }
    }
}

extern "C" void kernel_launch(void* const* d_in, const int* in_sizes, int n_in,
                              void* d_out, int out_size, void* d_ws, size_t ws_size,
                              hipStream_t stream) {
    const float* X     = (const float*)d_in[0];
    const float* W     = (const float*)d_in[2];
    const float* bias  = (const float*)d_in[3];
    const float* gamma = (const float*)d_in[4];
    const float* beta  = (const float*)d_in[5];

    float* E      = (float*)d_out;                              // B*N*K*F floats
    float* EidxF  = (float*)d_out + (size_t)B_ * N_ * K_ * F_;  // B*N*K floats

    int nodes = B_ * N_;

    hipLaunchKernelGGL(fused_kernel, dim3(nodes / 4), dim3(256), 0, stream,
                       X, W, bias, gamma, beta, E, EidxF);
}

// Round 8
// 51.263 us; speedup vs baseline: 1.1946x; 1.1946x over previous
//
#include <hip/hip_runtime.h>
#include <stdint.h>

#define B_ 4
#define N_ 2048
#define K_ 30
#define F_ 128
#define NF 39

typedef unsigned long long u64;
typedef float f32x4 __attribute__((ext_vector_type(4)));
typedef short s16x8 __attribute__((ext_vector_type(8)));

__device__ __forceinline__ u64 umin64(u64 a, u64 b) { return a < b ? a : b; }

template <int CTRL>
__device__ __forceinline__ float dpp_add(float x) {
    int r = __builtin_amdgcn_update_dpp(0, __float_as_int(x), CTRL, 0xF, 0xF, true);
    return x + __int_as_float(r);
}
// sum over the 16 lanes of a DPP row (all lanes get the row total)
__device__ __forceinline__ float rowsum16(float x) {
    x = dpp_add<0xB1>(x);    // quad_perm [1,0,3,2]
    x = dpp_add<0x4E>(x);    // quad_perm [2,3,0,1]
    x = dpp_add<0x141>(x);   // row_half_mirror
    x = dpp_add<0x140>(x);   // row_mirror
    return x;
}

__device__ __forceinline__ unsigned int bf16rne(float f) {
    unsigned int u = __float_as_uint(f);
    return (u + 0x7FFFu + ((u >> 16) & 1u)) >> 16;
}
__device__ __forceinline__ unsigned int bfpack(float a, float b) {
    return bf16rne(a) | (bf16rne(b) << 16);
}

// ---- Kernel B: top-30 (wave/node) + fused per-node frames O9 ----
// Selection in bits(ssq+eps) domain (monotone with D); cutoff = 30th-smallest
// lane-min (+64 ulp slack for sqrt-rounding collisions). Survivors get exact D
// and exact (D, idx) rank via LDS-broadcast counting (no serial sort chain).
__global__ __launch_bounds__(256) void topk_kernel(const float* __restrict__ X,
                                                   float* __restrict__ O9,
                                                   int* __restrict__ Eidx,
                                                   float* __restrict__ Dn,
                                                   float* __restrict__ EidxF) {
    __shared__ float xs[N_], ys[N_], zs[N_];   // 24 KB SoA
    __shared__ u64 surv[4][64];
    int t = threadIdx.x, lane = t & 63, wid = t >> 6;
    int node = blockIdx.x * 4 + wid;
    int i = node & (N_ - 1);
    const float* Xb = X + (size_t)(node - i) * 3;   // batch base

    for (int idx = t; idx < 3 * N_; idx += 256) {
        float v = Xb[idx];
        int j = idx / 3, c = idx - 3 * j;
        if (c == 0) xs[j] = v; else if (c == 1) ys[j] = v; else zs[j] = v;
    }
    __syncthreads();

    // frames for this block's 4 nodes (threads 0..3) from LDS coords
    if (t < 4) {
        int nn = blockIdx.x * 4 + t;
        int ii = nn & (N_ - 1);
        float o[9] = {0.f,0.f,0.f,0.f,0.f,0.f,0.f,0.f,0.f};
        if (ii >= 1 && ii <= N_ - 3) {
            float ax = xs[ii-1], ay = ys[ii-1], az = zs[ii-1];
            float bx = xs[ii],   by = ys[ii],   bz = zs[ii];
            float cx = xs[ii+1], cy = ys[ii+1], cz = zs[ii+1];
            float u2x = bx-ax, u2y = by-ay, u2z = bz-az;
            float n2_ = sqrtf(u2x*u2x+u2y*u2y+u2z*u2z);
            float inv = 1.0f / fmaxf(n2_, 1e-12f);
            u2x*=inv; u2y*=inv; u2z*=inv;
            float u1x = cx-bx, u1y = cy-by, u1z = cz-bz;
            float n1_ = sqrtf(u1x*u1x+u1y*u1y+u1z*u1z);
            inv = 1.0f / fmaxf(n1_, 1e-12f);
            u1x*=inv; u1y*=inv; u1z*=inv;
            float nx = u2y*u1z - u2z*u1y;
            float ny = u2z*u1x - u2x*u1z;
            float nz = u2x*u1y - u2y*u1x;
            float nn2 = sqrtf(nx*nx+ny*ny+nz*nz);
            inv = 1.0f / fmaxf(nn2, 1e-12f);
            nx*=inv; ny*=inv; nz*=inv;
            float ox = u2x-u1x, oy = u2y-u1y, oz = u2z-u1z;
            float no = sqrtf(ox*ox+oy*oy+oz*oz);
            inv = 1.0f / fmaxf(no, 1e-12f);
            ox*=inv; oy*=inv; oz*=inv;
            o[0]=ox; o[1]=oy; o[2]=oz;
            o[3]=nx; o[4]=ny; o[5]=nz;
            o[6]=oy*nz - oz*ny; o[7]=oz*nx - ox*nz; o[8]=ox*ny - oy*nx;
        }
        float* dst = O9 + (size_t)nn * 9;
        #pragma unroll
        for (int q = 0; q < 9; ++q) dst[q] = o[q];
    }

    float xi = xs[i], yi = ys[i], zi = zs[i];

    unsigned int d[32];
    #pragma unroll
    for (int s = 0; s < 32; ++s) {
        int j = lane + (s << 6);
        float dx = __fsub_rn(xs[j], xi);
        float dy = __fsub_rn(ys[j], yi);
        float dz = __fsub_rn(zs[j], zi);
        float s1 = __fadd_rn(__fmul_rn(dx,dx), __fmul_rn(dy,dy));
        float s2 = __fadd_rn(s1, __fmul_rn(dz,dz));
        d[s] = __float_as_uint(__fadd_rn(s2, 1e-6f));   // bits(ssq+eps)
    }

    unsigned int lm = d[0];
    #pragma unroll
    for (int s = 1; s < 32; ++s) lm = min(lm, d[s]);

    // bitonic sort of 64 lane-minima (32-bit, ascending)
    unsigned int v32 = lm;
    #pragma unroll
    for (int k = 2; k <= 64; k <<= 1) {
        #pragma unroll
        for (int j = k >> 1; j >= 1; j >>= 1) {
            unsigned int o = (unsigned int)__shfl_xor((int)v32, j, 64);
            bool up = ((lane & k) == 0);
            bool lower = ((lane & j) == 0);
            v32 = (lower == up) ? min(v32, o) : max(v32, o);
        }
    }
    unsigned int Bcut = (unsigned int)__shfl((int)v32, K_ - 1, 64) + 64u;  // slack

    // ballot-compact survivors (exact D keys)
    int base = 0;
    #pragma unroll
    for (int s = 0; s < 32; ++s) {
        bool p = (d[s] <= Bcut);
        u64 blt = __ballot(p);
        if (p) {
            int slot = base + (int)__popcll(blt & ((1ull << lane) - 1ull));
            if (slot < 64) {
                float D = __fsqrt_rn(__uint_as_float(d[s]));   // exact reference D
                surv[wid][slot] = (((u64)__float_as_uint(D)) << 32)
                                | (unsigned int)(lane + (s << 6));
            }
        }
        base += (int)__popcll(blt);
    }
    int cnt = base;

    if (cnt <= 64) {
        if (lane == 0 && cnt < 64) surv[wid][cnt] = ~0ull;  // pad for pair reads
        u64 my = surv[wid][lane];
        // exact rank via broadcast reads (pipelined, no serial chain)
        int rank = 0;
        for (int r = 0; r < cnt; r += 2) {
            ulonglong2 kk = *(const ulonglong2*)&surv[wid][r];
            rank += (kk.x < my) ? 1 : 0;
            rank += (kk.y < my) ? 1 : 0;   // pad slot ~0ull never counts
        }
        if (lane < cnt && rank < K_) {
            int j = (int)(my & 0xffffffffull);
            int o = node * K_ + rank;
            Eidx[o] = j;
            Dn[o] = __uint_as_float((unsigned int)(my >> 32));
            EidxF[o] = (float)j;
        }
    } else {
        // exact fallback: convert keys to D-bits, 30 sequential extractions
        #pragma unroll
        for (int s = 0; s < 32; ++s)
            d[s] = __float_as_uint(__fsqrt_rn(__uint_as_float(d[s])));
        for (int k = 0; k < K_; ++k) {
            u64 m = ~0ull;
            #pragma unroll
            for (int s = 0; s < 32; ++s) {
                u64 kk = (((u64)d[s]) << 32) | (unsigned int)(lane + (s << 6));
                m = umin64(m, kk);
            }
            #pragma unroll
            for (int off = 1; off < 64; off <<= 1)
                m = umin64(m, (u64)__shfl_xor((long long)m, off, 64));
            #pragma unroll
            for (int s = 0; s < 32; ++s) {
                u64 kk = (((u64)d[s]) << 32) | (unsigned int)(lane + (s << 6));
                if (kk == m) d[s] = 0xFFFFFFFFu;
            }
            if (lane == 0) {
                int o = node * K_ + k;
                int j = (int)(m & 0xffffffffull);
                Eidx[o] = j;
                Dn[o] = __uint_as_float((unsigned int)(m >> 32));
                EidxF[o] = (float)j;
            }
        }
    }
}

// ------- Kernel C: features -> bf16 MFMA 39x128 matmul -> LayerNorm -------
__global__ __launch_bounds__(256) void edge_fused(const float* __restrict__ X,
                                                  const float* __restrict__ O9,
                                                  const int* __restrict__ Eidx,
                                                  const float* __restrict__ Dn,
                                                  const float* __restrict__ W,
                                                  const float* __restrict__ bias,
                                                  const float* __restrict__ gamma,
                                                  const float* __restrict__ beta,
                                                  float* __restrict__ E) {
    __shared__ unsigned int ldsF[128 * 32];  // [edge][64 bf16 k], XOR-swizzled 16B slots
    __shared__ unsigned int ldsW[128 * 32];  // [col][64 bf16 k],  XOR-swizzled
    int t = threadIdx.x, lane = t & 63, wid = t >> 6;
    int e0 = blockIdx.x * 128;

    if (t < 128) {
        // ---- features for edge e0+t ----
        int e = e0 + t;
        int b = e / (N_ * K_);
        int rem = e - b * (N_ * K_);
        int i = rem / K_;
        int node = b * N_ + i;
        int j = Eidx[e];
        float dnb = Dn[e];

        float f[40];
        float dd = (float)(j - i);
        const float freqs[8] = {1.0f, 0.31622776601683794f, 0.1f, 0.031622776601683794f,
                                0.01f, 0.0031622776601683794f, 0.001f, 0.00031622776601683794f};
        #pragma unroll
        for (int l = 0; l < 8; ++l) {
            float a = dd * freqs[l];
            float sv, cv;
            __sincosf(a, &sv, &cv);
            f[l] = cv;
            f[8 + l] = sv;
        }
        #pragma unroll
        for (int r = 0; r < 16; ++r) {
            float mu = (20.0f / 15.0f) * (float)r;
            float u = (dnb - mu) * 0.8f;
            f[16 + r] = __expf(-u * u);
        }
        const float* Omp = O9 + (size_t)node * 9;
        float Om[9];
        #pragma unroll
        for (int q = 0; q < 9; ++q) Om[q] = Omp[q];
        const float* Xi = X + (size_t)node * 3;
        const float* Xj = X + (size_t)(b * N_ + j) * 3;
        float dx = Xj[0] - Xi[0], dy = Xj[1] - Xi[1], dz = Xj[2] - Xi[2];
        float v0 = Om[0]*dx + Om[1]*dy + Om[2]*dz;
        float v1 = Om[3]*dx + Om[4]*dy + Om[5]*dz;
        float v2 = Om[6]*dx + Om[7]*dy + Om[8]*dz;
        float n = sqrtf(v0*v0 + v1*v1 + v2*v2);
        float inv = 1.0f / fmaxf(n, 1e-12f);
        f[32] = v0 * inv; f[33] = v1 * inv; f[34] = v2 * inv;
        const float* On = O9 + (size_t)(b * N_ + j) * 9;
        float R00 = Om[0]*On[0] + Om[3]*On[3] + Om[6]*On[6];
        float R01 = Om[0]*On[1] + Om[3]*On[4] + Om[6]*On[7];
        float R02 = Om[0]*On[2] + Om[3]*On[5] + Om[6]*On[8];
        float R10 = Om[1]*On[0] + Om[4]*On[3] + Om[7]*On[6];
        float R11 = Om[1]*On[1] + Om[4]*On[4] + Om[7]*On[7];
        float R12 = Om[1]*On[2] + Om[4]*On[5] + Om[7]*On[8];
        float R20 = Om[2]*On[0] + Om[5]*On[3] + Om[8]*On[6];
        float R21 = Om[2]*On[1] + Om[5]*On[4] + Om[8]*On[7];
        float R22 = Om[2]*On[2] + Om[5]*On[5] + Om[8]*On[8];
        float mg0 = 0.5f * sqrtf(fabsf(1.0f + R00 - R11 - R22));
        float mg1 = 0.5f * sqrtf(fabsf(1.0f - R00 + R11 - R22));
        float mg2 = 0.5f * sqrtf(fabsf(1.0f - R00 - R11 + R22));
        float t0 = R21 - R12, t1 = R02 - R20, t2 = R10 - R01;
        float s0 = (t0 > 0.f) ? 1.f : ((t0 < 0.f) ? -1.f : 0.f);
        float s1 = (t1 > 0.f) ? 1.f : ((t1 < 0.f) ? -1.f : 0.f);
        float s2 = (t2 > 0.f) ? 1.f : ((t2 < 0.f) ? -1.f : 0.f);
        float q0 = s0 * mg0, q1 = s1 * mg1, q2 = s2 * mg2;
        float w = sqrtf(fmaxf(1.0f + R00 + R11 + R22, 0.0f)) * 0.5f;
        float nq = sqrtf(q0*q0 + q1*q1 + q2*q2 + w*w);
        inv = 1.0f / fmaxf(nq, 1e-12f);
        f[35] = q0 * inv; f[36] = q1 * inv; f[37] = q2 * inv; f[38] = w * inv;
        f[39] = 0.0f;

        int row = t;
        #pragma unroll
        for (int c = 0; c < 8; ++c) {
            uint4 u;
            if (c < 5) {
                u.x = bfpack(f[8*c+0], f[8*c+1]);
                u.y = bfpack(f[8*c+2], f[8*c+3]);
                u.z = bfpack(f[8*c+4], f[8*c+5]);
                u.w = bfpack(f[8*c+6], f[8*c+7]);
            } else {
                u = make_uint4(0u, 0u, 0u, 0u);
            }
            int idx = row * 32 + ((4 * c) ^ ((row & 7) << 2));
            *(uint4*)&ldsF[idx] = u;
        }
    } else {
        // ---- stage W: bf16 [col][k] (K padded to 64), b128 writes, same swizzle ----
        int col = t - 128;
        #pragma unroll
        for (int c8 = 0; c8 < 8; ++c8) {
            uint4 u;
            unsigned int* up = (unsigned int*)&u;
            #pragma unroll
            for (int m = 0; m < 4; ++m) {
                int k0 = 8 * c8 + 2 * m, k1 = k0 + 1;
                float a  = (k0 < NF) ? W[k0 * F_ + col] : 0.f;
                float bv = (k1 < NF) ? W[k1 * F_ + col] : 0.f;
                up[m] = bfpack(a, bv);
            }
            int idx = col * 32 + ((4 * c8) ^ ((col & 7) << 2));
            *(uint4*)&ldsW[idx] = u;
        }
    }

    float gg[8], be8[8], bb[8];
    #pragma unroll
    for (int tt = 0; tt < 8; ++tt) {
        int c = 16 * tt + (lane & 15);
        gg[tt] = gamma[c]; be8[tt] = beta[c]; bb[tt] = bias[c];
    }

    __syncthreads();

    s16x8 wf[8][2];
    #pragma unroll
    for (int tt = 0; tt < 8; ++tt) {
        int col = 16 * tt + (lane & 15);
        #pragma unroll
        for (int s = 0; s < 2; ++s) {
            int idx = col * 32 + ((((lane >> 4) * 4) + s * 16) ^ ((col & 7) << 2));
            wf[tt][s] = *(s16x8*)&ldsW[idx];
        }
    }

    #pragma unroll
    for (int wt = 0; wt < 2; ++wt) {
        int ebase = wid * 32 + wt * 16;
        int arow = ebase + (lane & 15);
        s16x8 af[2];
        #pragma unroll
        for (int s = 0; s < 2; ++s) {
            int idx = arow * 32 + ((((lane >> 4) * 4) + s * 16) ^ ((arow & 7) << 2));
            af[s] = *(s16x8*)&ldsF[idx];
        }
        f32x4 acc[8];
        #pragma unroll
        for (int tt = 0; tt < 8; ++tt) {
            acc[tt] = (f32x4){0.f, 0.f, 0.f, 0.f};
            acc[tt] = __builtin_amdgcn_mfma_f32_16x16x32_bf16(af[0], wf[tt][0], acc[tt], 0, 0, 0);
            acc[tt] = __builtin_amdgcn_mfma_f32_16x16x32_bf16(af[1], wf[tt][1], acc[tt], 0, 0, 0);
        }
        float sum[4] = {0,0,0,0}, sq[4] = {0,0,0,0};
        #pragma unroll
        for (int tt = 0; tt < 8; ++tt) {
            #pragma unroll
            for (int q = 0; q < 4; ++q) {
                float v = acc[tt][q] + bb[tt];
                acc[tt][q] = v;
                sum[q] += v;
                sq[q] = fmaf(v, v, sq[q]);
            }
        }
        float muv[4], invv[4];
        #pragma unroll
        for (int q = 0; q < 4; ++q) {
            float S  = rowsum16(sum[q]);
            float Qs = rowsum16(sq[q]);
            float mu = S * (1.0f / 128.0f);
            float var = (Qs - S * mu) * (1.0f / 127.0f);
            muv[q] = mu;
            invv[q] = 1.0f / (sqrtf(var + 1e-6f) + 1e-6f);
        }
        size_t base = (size_t)(e0 + ebase) * F_;
        #pragma unroll
        for (int tt = 0; tt < 8; ++tt) {
            int c = 16 * tt + (lane & 15);
            #pragma unroll
            for (int q = 0; q < 4; ++q) {
                int er = (lane >> 4) * 4 + q;
                E[base + (size_t)er * F_ + c] =
                    gg[tt] * (acc[tt][q] - muv[q]) * invv[q] + be8[tt];
            }
        }
    }
}

extern "C" void kernel_launch(void* const* d_in, const int* in_sizes, int n_in,
                              void* d_out, int out_size, void* d_ws, size_t ws_size,
                              hipStream_t stream) {
    const float* X     = (const float*)d_in[0];
    const float* W     = (const float*)d_in[2];
    const float* bias  = (const float*)d_in[3];
    const float* gamma = (const float*)d_in[4];
    const float* beta  = (const float*)d_in[5];

    float* E      = (float*)d_out;                              // B*N*K*F floats
    float* EidxF  = (float*)d_out + (size_t)B_ * N_ * K_ * F_;  // B*N*K floats

    float* O9   = (float*)d_ws;                          // B*N*9
    int*   Eidx = (int*)(O9 + (size_t)B_ * N_ * 9);      // B*N*K
    float* Dn   = (float*)(Eidx + (size_t)B_ * N_ * K_); // B*N*K

    int nodes = B_ * N_;
    int edges = nodes * K_;

    hipLaunchKernelGGL(topk_kernel, dim3(nodes / 4), dim3(256), 0, stream,
                       X, O9, Eidx, Dn, EidxF);
    hipLaunchKernelGGL(edge_fused, dim3(edges / 128), dim3(256), 0, stream,
                       X, O9, Eidx, Dn, W, bias, gamma, beta, E);
}

// Round 9
// 47.067 us; speedup vs baseline: 1.3011x; 1.0892x over previous
//
#include <hip/hip_runtime.h>
#include <stdint.h>

#define B_ 4
#define N_ 2048
#define K_ 30
#define F_ 128
#define NF 39

typedef unsigned long long u64;
typedef float f32x4 __attribute__((ext_vector_type(4)));
typedef short s16x8 __attribute__((ext_vector_type(8)));

__device__ __forceinline__ u64 umin64(u64 a, u64 b) { return a < b ? a : b; }

template <int CTRL>
__device__ __forceinline__ float dpp_add(float x) {
    int r = __builtin_amdgcn_update_dpp(0, __float_as_int(x), CTRL, 0xF, 0xF, true);
    return x + __int_as_float(r);
}
// sum over the 16 lanes of a DPP row (all lanes get the row total)
__device__ __forceinline__ float rowsum16(float x) {
    x = dpp_add<0xB1>(x);    // quad_perm [1,0,3,2]
    x = dpp_add<0x4E>(x);    // quad_perm [2,3,0,1]
    x = dpp_add<0x141>(x);   // row_half_mirror
    x = dpp_add<0x140>(x);   // row_mirror
    return x;
}

__device__ __forceinline__ unsigned int bf16rne(float f) {
    unsigned int u = __float_as_uint(f);
    return (u + 0x7FFFu + ((u >> 16) & 1u)) >> 16;
}
__device__ __forceinline__ unsigned int bfpack(float a, float b) {
    return bf16rne(a) | (bf16rne(b) << 16);
}

// ---- Kernel B: top-30, 8 nodes per 512-thread block (wave per node) ----
// Selection in bits(ssq+eps) domain (monotone with D); cutoff = 30th-smallest
// lane-min (+64 ulp slack for sqrt-rounding collisions). Survivors get exact D
// and exact (D, idx) rank via LDS-broadcast counting (no serial sort chain).
__global__ __launch_bounds__(512, 6) void topk_kernel(const float* __restrict__ X,
                                                      float* __restrict__ O9,
                                                      int* __restrict__ Eidx,
                                                      float* __restrict__ Dn,
                                                      float* __restrict__ EidxF) {
    __shared__ float4 P[N_];          // 32 KB
    __shared__ u64 surv[8][64];       // 4 KB
    int t = threadIdx.x, lane = t & 63, wid = t >> 6;   // wid 0..7
    int node = blockIdx.x * 8 + wid;
    int i = node & (N_ - 1);
    const float* Xb = X + (size_t)(node - i) * 3;   // batch base
    float* Pf = (float*)P;

    // stage X[batch] into LDS float4 (12 dwords per thread, coalesced)
    #pragma unroll
    for (int r = 0; r < 12; ++r) {
        int idx = t + r * 512;
        float v = Xb[idx];
        int j = idx / 3, c = idx - 3 * j;
        Pf[4 * j + c] = v;
    }
    __syncthreads();

    // frames for this block's 8 nodes (threads 0..7) from LDS coords
    if (t < 8) {
        int nn = blockIdx.x * 8 + t;
        int ii = nn & (N_ - 1);
        float o[9] = {0.f,0.f,0.f,0.f,0.f,0.f,0.f,0.f,0.f};
        if (ii >= 1 && ii <= N_ - 3) {
            float4 A = P[ii-1], Bv = P[ii], C = P[ii+1];
            float u2x = Bv.x-A.x, u2y = Bv.y-A.y, u2z = Bv.z-A.z;
            float n2_ = sqrtf(u2x*u2x+u2y*u2y+u2z*u2z);
            float inv = 1.0f / fmaxf(n2_, 1e-12f);
            u2x*=inv; u2y*=inv; u2z*=inv;
            float u1x = C.x-Bv.x, u1y = C.y-Bv.y, u1z = C.z-Bv.z;
            float n1_ = sqrtf(u1x*u1x+u1y*u1y+u1z*u1z);
            inv = 1.0f / fmaxf(n1_, 1e-12f);
            u1x*=inv; u1y*=inv; u1z*=inv;
            float nx = u2y*u1z - u2z*u1y;
            float ny = u2z*u1x - u2x*u1z;
            float nz = u2x*u1y - u2y*u1x;
            float nn2 = sqrtf(nx*nx+ny*ny+nz*nz);
            inv = 1.0f / fmaxf(nn2, 1e-12f);
            nx*=inv; ny*=inv; nz*=inv;
            float ox = u2x-u1x, oy = u2y-u1y, oz = u2z-u1z;
            float no = sqrtf(ox*ox+oy*oy+oz*oz);
            inv = 1.0f / fmaxf(no, 1e-12f);
            ox*=inv; oy*=inv; oz*=inv;
            o[0]=ox; o[1]=oy; o[2]=oz;
            o[3]=nx; o[4]=ny; o[5]=nz;
            o[6]=oy*nz - oz*ny; o[7]=oz*nx - ox*nz; o[8]=ox*ny - oy*nx;
        }
        float* dst = O9 + (size_t)nn * 9;
        #pragma unroll
        for (int q = 0; q < 9; ++q) dst[q] = o[q];
    }

    float4 ci = P[i];
    float xi = ci.x, yi = ci.y, zi = ci.z;

    unsigned int d[32];
    #pragma unroll
    for (int s = 0; s < 32; ++s) {
        float4 p = P[lane + (s << 6)];
        float dx = __fsub_rn(p.x, xi);
        float dy = __fsub_rn(p.y, yi);
        float dz = __fsub_rn(p.z, zi);
        float s1 = __fadd_rn(__fmul_rn(dx,dx), __fmul_rn(dy,dy));
        float s2 = __fadd_rn(s1, __fmul_rn(dz,dz));
        d[s] = __float_as_uint(__fadd_rn(s2, 1e-6f));   // bits(ssq+eps)
    }

    unsigned int lm = d[0];
    #pragma unroll
    for (int s = 1; s < 32; ++s) lm = min(lm, d[s]);

    // bitonic sort of 64 lane-minima (32-bit, ascending) within the wave
    unsigned int v32 = lm;
    #pragma unroll
    for (int k = 2; k <= 64; k <<= 1) {
        #pragma unroll
        for (int j = k >> 1; j >= 1; j >>= 1) {
            unsigned int o = (unsigned int)__shfl_xor((int)v32, j, 64);
            bool up = ((lane & k) == 0);
            bool lower = ((lane & j) == 0);
            v32 = (lower == up) ? min(v32, o) : max(v32, o);
        }
    }
    unsigned int Bcut = (unsigned int)__shfl((int)v32, K_ - 1, 64) + 64u;  // slack

    // ballot-compact survivors (exact D keys)
    int base = 0;
    #pragma unroll
    for (int s = 0; s < 32; ++s) {
        bool p = (d[s] <= Bcut);
        u64 blt = __ballot(p);
        if (p) {
            int slot = base + (int)__popcll(blt & ((1ull << lane) - 1ull));
            if (slot < 64) {
                float D = __fsqrt_rn(__uint_as_float(d[s]));   // exact reference D
                surv[wid][slot] = (((u64)__float_as_uint(D)) << 32)
                                | (unsigned int)(lane + (s << 6));
            }
        }
        base += (int)__popcll(blt);
    }
    int cnt = base;

    if (cnt <= 64) {
        if (lane == 0 && cnt < 64) surv[wid][cnt] = ~0ull;  // pad for pair reads
        u64 my = surv[wid][lane];
        // exact rank via broadcast pair reads (pipelined, no serial chain)
        int rank = 0;
        for (int r = 0; r < cnt; r += 2) {
            ulonglong2 kk = *(const ulonglong2*)&surv[wid][r];
            rank += (kk.x < my) ? 1 : 0;
            rank += (kk.y < my) ? 1 : 0;   // pad slot ~0ull never counts
        }
        if (lane < cnt && rank < K_) {
            int j = (int)(my & 0xffffffffull);
            int o = node * K_ + rank;
            Eidx[o] = j;
            Dn[o] = __uint_as_float((unsigned int)(my >> 32));
            EidxF[o] = (float)j;
        }
    } else {
        // exact fallback: convert keys to D-bits, 30 sequential extractions
        #pragma unroll
        for (int s = 0; s < 32; ++s)
            d[s] = __float_as_uint(__fsqrt_rn(__uint_as_float(d[s])));
        for (int k = 0; k < K_; ++k) {
            u64 m = ~0ull;
            #pragma unroll
            for (int s = 0; s < 32; ++s) {
                u64 kk = (((u64)d[s]) << 32) | (unsigned int)(lane + (s << 6));
                m = umin64(m, kk);
            }
            #pragma unroll
            for (int off = 1; off < 64; off <<= 1)
                m = umin64(m, (u64)__shfl_xor((long long)m, off, 64));
            #pragma unroll
            for (int s = 0; s < 32; ++s) {
                u64 kk = (((u64)d[s]) << 32) | (unsigned int)(lane + (s << 6));
                if (kk == m) d[s] = 0xFFFFFFFFu;
            }
            if (lane == 0) {
                int o = node * K_ + k;
                int j = (int)(m & 0xffffffffull);
                Eidx[o] = j;
                Dn[o] = __uint_as_float((unsigned int)(m >> 32));
                EidxF[o] = (float)j;
            }
        }
    }
}

// ------- Kernel C: features -> bf16 MFMA 39x128 matmul -> LayerNorm -------
__global__ __launch_bounds__(256) void edge_fused(const float* __restrict__ X,
                                                  const float* __restrict__ O9,
                                                  const int* __restrict__ Eidx,
                                                  const float* __restrict__ Dn,
                                                  const float* __restrict__ W,
                                                  const float* __restrict__ bias,
                                                  const float* __restrict__ gamma,
                                                  const float* __restrict__ beta,
                                                  float* __restrict__ E) {
    __shared__ unsigned int ldsF[128 * 32];  // [edge][64 bf16 k], XOR-swizzled 16B slots
    __shared__ unsigned int ldsW[128 * 32];  // [col][64 bf16 k],  XOR-swizzled
    int t = threadIdx.x, lane = t & 63, wid = t >> 6;
    int e0 = blockIdx.x * 128;

    if (t < 128) {
        // ---- features for edge e0+t ----
        int e = e0 + t;
        int b = e / (N_ * K_);
        int rem = e - b * (N_ * K_);
        int i = rem / K_;
        int node = b * N_ + i;
        int j = Eidx[e];
        float dnb = Dn[e];

        float f[40];
        float dd = (float)(j - i);
        const float freqs[8] = {1.0f, 0.31622776601683794f, 0.1f, 0.031622776601683794f,
                                0.01f, 0.0031622776601683794f, 0.001f, 0.00031622776601683794f};
        #pragma unroll
        for (int l = 0; l < 8; ++l) {
            float a = dd * freqs[l];
            float sv, cv;
            __sincosf(a, &sv, &cv);
            f[l] = cv;
            f[8 + l] = sv;
        }
        #pragma unroll
        for (int r = 0; r < 16; ++r) {
            float mu = (20.0f / 15.0f) * (float)r;
            float u = (dnb - mu) * 0.8f;
            f[16 + r] = __expf(-u * u);
        }
        const float* Omp = O9 + (size_t)node * 9;
        float Om[9];
        #pragma unroll
        for (int q = 0; q < 9; ++q) Om[q] = Omp[q];
        const float* Xi = X + (size_t)node * 3;
        const float* Xj = X + (size_t)(b * N_ + j) * 3;
        float dx = Xj[0] - Xi[0], dy = Xj[1] - Xi[1], dz = Xj[2] - Xi[2];
        float v0 = Om[0]*dx + Om[1]*dy + Om[2]*dz;
        float v1 = Om[3]*dx + Om[4]*dy + Om[5]*dz;
        float v2 = Om[6]*dx + Om[7]*dy + Om[8]*dz;
        float n = sqrtf(v0*v0 + v1*v1 + v2*v2);
        float inv = 1.0f / fmaxf(n, 1e-12f);
        f[32] = v0 * inv; f[33] = v1 * inv; f[34] = v2 * inv;
        const float* On = O9 + (size_t)(b * N_ + j) * 9;
        float R00 = Om[0]*On[0] + Om[3]*On[3] + Om[6]*On[6];
        float R01 = Om[0]*On[1] + Om[3]*On[4] + Om[6]*On[7];
        float R02 = Om[0]*On[2] + Om[3]*On[5] + Om[6]*On[8];
        float R10 = Om[1]*On[0] + Om[4]*On[3] + Om[7]*On[6];
        float R11 = Om[1]*On[1] + Om[4]*On[4] + Om[7]*On[7];
        float R12 = Om[1]*On[2] + Om[4]*On[5] + Om[7]*On[8];
        float R20 = Om[2]*On[0] + Om[5]*On[3] + Om[8]*On[6];
        float R21 = Om[2]*On[1] + Om[5]*On[4] + Om[8]*On[7];
        float R22 = Om[2]*On[2] + Om[5]*On[5] + Om[8]*On[8];
        float mg0 = 0.5f * sqrtf(fabsf(1.0f + R00 - R11 - R22));
        float mg1 = 0.5f * sqrtf(fabsf(1.0f - R00 + R11 - R22));
        float mg2 = 0.5f * sqrtf(fabsf(1.0f - R00 - R11 + R22));
        float t0 = R21 - R12, t1 = R02 - R20, t2 = R10 - R01;
        float s0 = (t0 > 0.f) ? 1.f : ((t0 < 0.f) ? -1.f : 0.f);
        float s1 = (t1 > 0.f) ? 1.f : ((t1 < 0.f) ? -1.f : 0.f);
        float s2 = (t2 > 0.f) ? 1.f : ((t2 < 0.f) ? -1.f : 0.f);
        float q0 = s0 * mg0, q1 = s1 * mg1, q2 = s2 * mg2;
        float w = sqrtf(fmaxf(1.0f + R00 + R11 + R22, 0.0f)) * 0.5f;
        float nq = sqrtf(q0*q0 + q1*q1 + q2*q2 + w*w);
        inv = 1.0f / fmaxf(nq, 1e-12f);
        f[35] = q0 * inv; f[36] = q1 * inv; f[37] = q2 * inv; f[38] = w * inv;
        f[39] = 0.0f;

        int row = t;
        #pragma unroll
        for (int c = 0; c < 8; ++c) {
            uint4 u;
            if (c < 5) {
                u.x = bfpack(f[8*c+0], f[8*c+1]);
                u.y = bfpack(f[8*c+2], f[8*c+3]);
                u.z = bfpack(f[8*c+4], f[8*c+5]);
                u.w = bfpack(f[8*c+6], f[8*c+7]);
            } else {
                u = make_uint4(0u, 0u, 0u, 0u);
            }
            int idx = row * 32 + ((4 * c) ^ ((row & 7) << 2));
            *(uint4*)&ldsF[idx] = u;
        }
    } else {
        // ---- stage W: bf16 [col][k] (K padded to 64), b128 writes, same swizzle ----
        int col = t - 128;
        #pragma unroll
        for (int c8 = 0; c8 < 8; ++c8) {
            uint4 u;
            unsigned int* up = (unsigned int*)&u;
            #pragma unroll
            for (int m = 0; m < 4; ++m) {
                int k0 = 8 * c8 + 2 * m, k1 = k0 + 1;
                float a  = (k0 < NF) ? W[k0 * F_ + col] : 0.f;
                float bv = (k1 < NF) ? W[k1 * F_ + col] : 0.f;
                up[m] = bfpack(a, bv);
            }
            int idx = col * 32 + ((4 * c8) ^ ((col & 7) << 2));
            *(uint4*)&ldsW[idx] = u;
        }
    }

    float gg[8], be8[8], bb[8];
    #pragma unroll
    for (int tt = 0; tt < 8; ++tt) {
        int c = 16 * tt + (lane & 15);
        gg[tt] = gamma[c]; be8[tt] = beta[c]; bb[tt] = bias[c];
    }

    __syncthreads();

    s16x8 wf[8][2];
    #pragma unroll
    for (int tt = 0; tt < 8; ++tt) {
        int col = 16 * tt + (lane & 15);
        #pragma unroll
        for (int s = 0; s < 2; ++s) {
            int idx = col * 32 + ((((lane >> 4) * 4) + s * 16) ^ ((col & 7) << 2));
            wf[tt][s] = *(s16x8*)&ldsW[idx];
        }
    }

    #pragma unroll
    for (int wt = 0; wt < 2; ++wt) {
        int ebase = wid * 32 + wt * 16;
        int arow = ebase + (lane & 15);
        s16x8 af[2];
        #pragma unroll
        for (int s = 0; s < 2; ++s) {
            int idx = arow * 32 + ((((lane >> 4) * 4) + s * 16) ^ ((arow & 7) << 2));
            af[s] = *(s16x8*)&ldsF[idx];
        }
        f32x4 acc[8];
        #pragma unroll
        for (int tt = 0; tt < 8; ++tt) {
            acc[tt] = (f32x4){0.f, 0.f, 0.f, 0.f};
            acc[tt] = __builtin_amdgcn_mfma_f32_16x16x32_bf16(af[0], wf[tt][0], acc[tt], 0, 0, 0);
            acc[tt] = __builtin_amdgcn_mfma_f32_16x16x32_bf16(af[1], wf[tt][1], acc[tt], 0, 0, 0);
        }
        float sum[4] = {0,0,0,0}, sq[4] = {0,0,0,0};
        #pragma unroll
        for (int tt = 0; tt < 8; ++tt) {
            #pragma unroll
            for (int q = 0; q < 4; ++q) {
                float v = acc[tt][q] + bb[tt];
                acc[tt][q] = v;
                sum[q] += v;
                sq[q] = fmaf(v, v, sq[q]);
            }
        }
        float muv[4], invv[4];
        #pragma unroll
        for (int q = 0; q < 4; ++q) {
            float S  = rowsum16(sum[q]);
            float Qs = rowsum16(sq[q]);
            float mu = S * (1.0f / 128.0f);
            float var = (Qs - S * mu) * (1.0f / 127.0f);
            muv[q] = mu;
            invv[q] = 1.0f / (sqrtf(var + 1e-6f) + 1e-6f);
        }
        size_t base = (size_t)(e0 + ebase) * F_;
        #pragma unroll
        for (int tt = 0; tt < 8; ++tt) {
            int c = 16 * tt + (lane & 15);
            #pragma unroll
            for (int q = 0; q < 4; ++q) {
                int er = (lane >> 4) * 4 + q;
                E[base + (size_t)er * F_ + c] =
                    gg[tt] * (acc[tt][q] - muv[q]) * invv[q] + be8[tt];
            }
        }
    }
}

extern "C" void kernel_launch(void* const* d_in, const int* in_sizes, int n_in,
                              void* d_out, int out_size, void* d_ws, size_t ws_size,
                              hipStream_t stream) {
    const float* X     = (const float*)d_in[0];
    const float* W     = (const float*)d_in[2];
    const float* bias  = (const float*)d_in[3];
    const float* gamma = (const float*)d_in[4];
    const float* beta  = (const float*)d_in[5];

    float* E      = (float*)d_out;                              // B*N*K*F floats
    float* EidxF  = (float*)d_out + (size_t)B_ * N_ * K_ * F_;  // B*N*K floats

    float* O9   = (float*)d_ws;                          // B*N*9
    int*   Eidx = (int*)(O9 + (size_t)B_ * N_ * 9);      // B*N*K
    float* Dn   = (float*)(Eidx + (size_t)B_ * N_ * K_); // B*N*K

    int nodes = B_ * N_;
    int edges = nodes * K_;

    hipLaunchKernelGGL(topk_kernel, dim3(nodes / 8), dim3(512), 0, stream,
                       X, O9, Eidx, Dn, EidxF);
    hipLaunchKernelGGL(edge_fused, dim3(edges / 128), dim3(256), 0, stream,
                       X, O9, Eidx, Dn, W, bias, gamma, beta, E);
}